// Round 1
// baseline (389.583 us; speedup 1.0000x reference)
//
#include <hip/hip_runtime.h>

#define N_ 4
#define D_ 16
#define H_ 112
#define W_ 112
#define C_ 64

#define DO_ 2
#define HO_ 2
#define DT_ (D_ / DO_)                    // 8 d-tiles
#define HTILES (H_ / HO_)                 // 56 h-tiles
#define WAVES_PER_BLOCK 4
#define HGROUPS (HTILES / WAVES_PER_BLOCK) // 14
#define WSPLIT 2
#define WHALF (W_ / WSPLIT)               // 56

// Register sliding-window depthwise 3D conv.
// lane = channel (C=64 == wave width) -> every global access is 256B coalesced.
// Each wave: fixed (n, d0..d0+1, h0..h0+1), slides over 56 w columns keeping a
// 3-column x 4x4 (d,h) input window in registers. 16 loads / 108 FMA / 4 stores
// per step => ~4 input floats read per output (L1/L2 absorbs), HBM ~1x.
__global__ __launch_bounds__(256)
void dwconv3d_kernel(const float* __restrict__ x,
                     const float* __restrict__ wgt,
                     float* __restrict__ out) {
    int b = blockIdx.x;
    const int wh = b % WSPLIT; b /= WSPLIT;
    const int hg = b % HGROUPS; b /= HGROUPS;
    const int dt = b % DT_;     b /= DT_;
    const int n  = b;

    const int lane = threadIdx.x & 63;
    const int wid  = threadIdx.x >> 6;
    const int c    = lane;

    const int d0 = dt * DO_;
    const int h0 = (hg * WAVES_PER_BLOCK + wid) * HO_;
    const int w0 = wh * WHALF;

    // per-lane weights wt[kd][kh][kw] (27 VGPRs), coalesced 256B loads
    float wt[3][3][3];
#pragma unroll
    for (int kd = 0; kd < 3; ++kd)
#pragma unroll
      for (int kh = 0; kh < 3; ++kh)
#pragma unroll
        for (int kw = 0; kw < 3; ++kw)
          wt[kd][kh][kw] = wgt[((kd * 3 + kh) * 3 + kw) * C_ + c];

    // 16 input streams: clamped base pointer + {0,1} mask (loop-invariant)
    const float* px[4][4];
    float msk[4][4];
#pragma unroll
    for (int dr = 0; dr < 4; ++dr) {
      int d = d0 - 1 + dr;
      bool dv = (d >= 0) && (d < D_);
      int dc = d < 0 ? 0 : (d > D_ - 1 ? D_ - 1 : d);
#pragma unroll
      for (int hr = 0; hr < 4; ++hr) {
        int h = h0 - 1 + hr;
        bool hv = (h >= 0) && (h < H_);
        int hc = h < 0 ? 0 : (h > H_ - 1 ? H_ - 1 : h);
        msk[dr][hr] = (dv && hv) ? 1.0f : 0.0f;
        px[dr][hr] = x + (size_t)((n * D_ + dc) * H_ + hc) * W_ * C_ + c;
      }
    }

    // window: win[wslot][dr][hr], wslot 0/1/2 = cols w-1, w, w+1
    float win[3][4][4];

    if (w0 == 0) {
#pragma unroll
      for (int dr = 0; dr < 4; ++dr)
#pragma unroll
        for (int hr = 0; hr < 4; ++hr)
          win[0][dr][hr] = 0.0f;
    } else {
#pragma unroll
      for (int dr = 0; dr < 4; ++dr)
#pragma unroll
        for (int hr = 0; hr < 4; ++hr)
          win[0][dr][hr] = msk[dr][hr] * px[dr][hr][(size_t)(w0 - 1) * C_];
    }
#pragma unroll
    for (int dr = 0; dr < 4; ++dr)
#pragma unroll
      for (int hr = 0; hr < 4; ++hr) {
        win[1][dr][hr] = msk[dr][hr] * px[dr][hr][(size_t)(w0)     * C_];
        win[2][dr][hr] = msk[dr][hr] * px[dr][hr][(size_t)(w0 + 1) * C_];
      }

    // output pointers (all 4 outputs always in-range)
    float* po[2][2];
#pragma unroll
    for (int od = 0; od < 2; ++od)
#pragma unroll
      for (int oh = 0; oh < 2; ++oh)
        po[od][oh] = out + ((size_t)((n * D_ + d0 + od) * H_ + (h0 + oh)) * W_ + w0) * C_ + c;

    // advance stream pointers to the next column to load (w0+2)
#pragma unroll
    for (int dr = 0; dr < 4; ++dr)
#pragma unroll
      for (int hr = 0; hr < 4; ++hr)
        px[dr][hr] += (size_t)(w0 + 2) * C_;

#pragma unroll 4
    for (int w = w0; w < w0 + WHALF; ++w) {
      float acc[2][2];
#pragma unroll
      for (int od = 0; od < 2; ++od)
#pragma unroll
        for (int oh = 0; oh < 2; ++oh) {
          float a = 0.0f;
#pragma unroll
          for (int kw = 0; kw < 3; ++kw)
#pragma unroll
            for (int kd = 0; kd < 3; ++kd)
#pragma unroll
              for (int kh = 0; kh < 3; ++kh)
                a += win[kw][od + kd][oh + kh] * wt[kd][kh][kw];
          acc[od][oh] = a;
        }
#pragma unroll
      for (int od = 0; od < 2; ++od)
#pragma unroll
        for (int oh = 0; oh < 2; ++oh) {
          *po[od][oh] = acc[od][oh];
          po[od][oh] += C_;
        }
      // rotate window (copies vanish under unroll)
#pragma unroll
      for (int dr = 0; dr < 4; ++dr)
#pragma unroll
        for (int hr = 0; hr < 4; ++hr) {
          win[0][dr][hr] = win[1][dr][hr];
          win[1][dr][hr] = win[2][dr][hr];
        }
      if (w + 2 < W_) {  // wave-uniform
#pragma unroll
        for (int dr = 0; dr < 4; ++dr)
#pragma unroll
          for (int hr = 0; hr < 4; ++hr) {
            win[2][dr][hr] = msk[dr][hr] * px[dr][hr][0];
            px[dr][hr] += C_;
          }
      } else {
#pragma unroll
        for (int dr = 0; dr < 4; ++dr)
#pragma unroll
          for (int hr = 0; hr < 4; ++hr)
            win[2][dr][hr] = 0.0f;
      }
    }
}

extern "C" void kernel_launch(void* const* d_in, const int* in_sizes, int n_in,
                              void* d_out, int out_size, void* d_ws, size_t ws_size,
                              hipStream_t stream) {
    const float* x   = (const float*)d_in[0];
    const float* wgt = (const float*)d_in[1];
    float* out = (float*)d_out;

    dim3 grid(N_ * DT_ * HGROUPS * WSPLIT);  // 4*8*14*2 = 896 blocks
    dim3 block(256);
    dwconv3d_kernel<<<grid, block, 0, stream>>>(x, wgt, out);
}